// Round 5
// baseline (314.004 us; speedup 1.0000x reference)
//
#include <hip/hip_runtime.h>
#include <stdint.h>

// out[b,c] = sum_{k<256} batchs[b,k] * label2embed[c,k]
// A = batchs [16384, 256] fp32 row-major, Bm = label2embed [4096, 256] fp32 row-major
// out [16384, 4096] fp32. GEMM-BT, K=256. Output-write floor: 43.7 us (268 MB @ 6.3 TB/s).
//
// Session ledger:
//  R0: fill(~167, unconditional ws poison, fixed tax) + cvt(6) + gemm_bt(~124) = 297.
//  R1: cvt fused into gemm -> 50x VALU cvt blowup, gemm 186. REVERTED.
//  R2: no-LDS direct-from-L2 fragments -> gemm 206. REVERTED (global_load_lds wins).
//  R3: swapped-operand MFMA + f32x4 epilogue -> NEUTRAL (not store-issue-bound).
//  R4: triple-buf + counted vmcnt(4) pipeline -> NEUTRAL (not barrier-drain-bound).
//  R5 (this): remaining theory that fits the arithmetic: PLAIN output stores
//      write-allocate 268 MB through the 4 MB per-XCD L2s, evicting the B-panel
//      (2 MB, reused by all 512 blocks/XCD) between reuses -> ~250+ MB of input
//      re-fetch -> (268+260) MB @ 6.3 TB/s ~ 125 us = measured. Fix: NONTEMPORAL
//      epilogue stores (no-allocate, nt bit) so inputs stay L2-resident.
//      Structure otherwise identical to R3 (dbuf + __syncthreads).
#define MDIM 16384
#define NDIM 4096
#define KDIM 256

#define BM 128
#define BN 128
#define BK 32
#define KSTEPS (KDIM / BK)   // 8

typedef __attribute__((ext_vector_type(8))) short bf16x8;
typedef __attribute__((ext_vector_type(4))) float f32x4;

__device__ __forceinline__ unsigned short f2bf_rne(float f) {
    union { float f; uint32_t u; } v; v.f = f;
    uint32_t u = v.u;
    u += 0x7fffu + ((u >> 16) & 1u);   // round-to-nearest-even (finite inputs)
    return (unsigned short)(u >> 16);
}

// Pass 1: fp32 -> bf16 for both inputs, into workspace. 8 elems/thread, 16B stores.
// ws output is read immediately by the gemm -> PLAIN stores (want L2 residency).
__global__ __launch_bounds__(256) void cvt_kernel(const float* __restrict__ a,
                                                  const float* __restrict__ b,
                                                  unsigned short* __restrict__ wa,
                                                  unsigned short* __restrict__ wb) {
    const int64_t nA = (int64_t)MDIM * KDIM;
    int64_t i = ((int64_t)blockIdx.x * 256 + threadIdx.x) * 8;
    const float* src; unsigned short* dst; int64_t off;
    if (i < nA) { src = a; dst = wa; off = i; }
    else        { src = b; dst = wb; off = i - nA; }
    float4 f0 = *(const float4*)(src + off);
    float4 f1 = *(const float4*)(src + off + 4);
    union { unsigned short h[8]; int4 v; } o;
    o.h[0] = f2bf_rne(f0.x); o.h[1] = f2bf_rne(f0.y);
    o.h[2] = f2bf_rne(f0.z); o.h[3] = f2bf_rne(f0.w);
    o.h[4] = f2bf_rne(f1.x); o.h[5] = f2bf_rne(f1.y);
    o.h[6] = f2bf_rne(f1.z); o.h[7] = f2bf_rne(f1.w);
    *(int4*)(dst + off) = o.v;
}

// Stage one 128x32 bf16 tile of A and B into LDS via width-16 global_load_lds.
// chunk ch in [0,512): row = ch>>2, col = (ch&3)*8; LDS byte off = ch*16
// -> per-wave uniform base + lane*16 (matches global_load_lds HW placement).
__device__ __forceinline__ void stage_tiles(const unsigned short* __restrict__ Ab,
                                            const unsigned short* __restrict__ Bb,
                                            unsigned short* sA, unsigned short* sB,
                                            int tid, int k0) {
#pragma unroll
    for (int c = 0; c < 2; ++c) {
        int ch  = tid + c * 256;
        int row = ch >> 2;
        int col = (ch & 3) << 3;
        __builtin_amdgcn_global_load_lds(
            (const __attribute__((address_space(1))) void*)(Ab + (size_t)row * KDIM + k0 + col),
            (__attribute__((address_space(3))) void*)(sA + ch * 8), 16, 0, 0);
        __builtin_amdgcn_global_load_lds(
            (const __attribute__((address_space(1))) void*)(Bb + (size_t)row * KDIM + k0 + col),
            (__attribute__((address_space(3))) void*)(sB + ch * 8), 16, 0, 0);
    }
}

// Pass 2: bf16 MFMA GEMM-BT. 128x128 tile/block, 4 waves, each wave a 64x64 quadrant
// = 4x4 MFMA 16x16 tiles. BK=32, 8 K-steps, double-buffered LDS, one barrier/step.
// __launch_bounds__(256,4): cap VGPR<=128 -> 16 waves/CU (4 blocks/CU).
__global__ __launch_bounds__(256, 4) void gemm_bt(const unsigned short* __restrict__ A,
                                                  const unsigned short* __restrict__ Bm,
                                                  float* __restrict__ out) {
    __shared__ __align__(16) unsigned short sA[2][BM * BK];  // 2 x 8 KiB
    __shared__ __align__(16) unsigned short sB[2][BN * BK];  // 2 x 8 KiB

    const int tid  = threadIdx.x;
    const int lane = tid & 63;
    const int wave = tid >> 6;
    const int wm   = wave >> 1;
    const int wn   = wave & 1;
    const int quad = lane >> 4;
    const int r16  = lane & 15;

    // XCD-aware swizzle: xcd = blockIdx % 8. Each XCD owns a band of 16 bm's; bn sweeps
    // fastest -> per-XCD set = A band (1 MB) + full B (2 MB) = 3 MB < 4 MB XCD L2.
    const int id  = blockIdx.x;
    const int xcd = id & 7;
    const int g   = id >> 3;                // 0..511
    const int bm  = (xcd << 4) | (g >> 5);  // 0..127
    const int bn  = g & 31;                 // 0..31

    const unsigned short* Ab = A  + (size_t)bm * BM * KDIM;
    const unsigned short* Bb = Bm + (size_t)bn * BN * KDIM;

    f32x4 acc[4][4] = {};

    stage_tiles(Ab, Bb, sA[0], sB[0], tid, 0);

#pragma unroll
    for (int step = 0; step < KSTEPS; ++step) {
        __syncthreads();  // drains vmcnt for buf[step&1]; WAR-protects buf[(step+1)&1]
        if (step + 1 < KSTEPS)
            stage_tiles(Ab, Bb, sA[(step + 1) & 1], sB[(step + 1) & 1], tid, (step + 1) * BK);

        const unsigned short* cA = sA[step & 1];
        const unsigned short* cB = sB[step & 1];

        // Fragment: X[row = lane&15][k = quad*8 + j]  (one ds_read_b128 each)
        bf16x8 af[4], bfr[4];
#pragma unroll
        for (int i = 0; i < 4; ++i)
            af[i] = *(const bf16x8*)(cA + ((wm * 64 + i * 16 + r16) * BK + quad * 8));
#pragma unroll
        for (int j = 0; j < 4; ++j)
            bfr[j] = *(const bf16x8*)(cB + ((wn * 64 + j * 16 + r16) * BK + quad * 8));

        // SWAPPED operands (validated R1-R4): D = mfma(bfr, af) ->
        // D col-field (lane&15) = out row, D row-field (quad*4+reg) = out col.
#pragma unroll
        for (int i = 0; i < 4; ++i)
#pragma unroll
            for (int j = 0; j < 4; ++j)
                acc[i][j] = __builtin_amdgcn_mfma_f32_16x16x32_bf16(bfr[j], af[i], acc[i][j], 0, 0, 0);
    }

    // Epilogue: 16 dwordx4 NONTEMPORAL stores/lane. nt = no-allocate: the 268 MB
    // write-once stream must NOT evict the L2-resident A/B panels (the R5 theory).
#pragma unroll
    for (int i = 0; i < 4; ++i) {
        size_t row = (size_t)bm * BM + wm * 64 + i * 16 + r16;
#pragma unroll
        for (int j = 0; j < 4; ++j) {
            int col = bn * BN + wn * 64 + j * 16 + quad * 4;
            __builtin_nontemporal_store(acc[i][j], (f32x4*)(out + row * NDIM + col));
        }
    }
}

// Fallback (only if ws too small): fp32 dot, one thread per output.
__global__ __launch_bounds__(256) void naive_f32(const float* __restrict__ a,
                                                 const float* __restrict__ b,
                                                 float* __restrict__ out) {
    int64_t idx = (int64_t)blockIdx.x * 256 + threadIdx.x;
    int c = (int)(idx & (NDIM - 1));
    int r = (int)(idx >> 12);
    const float4* ap = (const float4*)(a + (size_t)r * KDIM);
    const float4* bp = (const float4*)(b + (size_t)c * KDIM);
    float s = 0.f;
#pragma unroll 8
    for (int k = 0; k < KDIM / 4; ++k) {
        float4 x = ap[k], y = bp[k];
        s += x.x * y.x + x.y * y.y + x.z * y.z + x.w * y.w;
    }
    out[idx] = s;
}

extern "C" void kernel_launch(void* const* d_in, const int* in_sizes, int n_in,
                              void* d_out, int out_size, void* d_ws, size_t ws_size,
                              hipStream_t stream) {
    const float* a = (const float*)d_in[0];   // batchs  [16384, 2, 128]
    const float* b = (const float*)d_in[1];   // label2embed [4096, 2, 128]
    float* out = (float*)d_out;               // [16384, 4096]

    const size_t need = ((size_t)MDIM + NDIM) * KDIM * sizeof(unsigned short); // 10.5 MB
    if (d_ws != nullptr && ws_size >= need) {
        unsigned short* wa = (unsigned short*)d_ws;
        unsigned short* wb = wa + (size_t)MDIM * KDIM;
        const int64_t nvec = ((int64_t)MDIM + NDIM) * KDIM / 8;  // 655,360
        cvt_kernel<<<(int)(nvec / 256), 256, 0, stream>>>(a, b, wa, wb);       // 2560 blocks
        gemm_bt<<<(MDIM / BM) * (NDIM / BN), 256, 0, stream>>>(wa, wb, out);   // 4096 blocks
    } else {
        naive_f32<<<(int64_t)MDIM * NDIM / 256, 256, 0, stream>>>(a, b, out);
    }
}

// Round 6
// 310.592 us; speedup vs baseline: 1.0110x; 1.0110x over previous
//
#include <hip/hip_runtime.h>
#include <stdint.h>

// out[b,c] = sum_{k<256} batchs[b,k] * label2embed[c,k]
// A = batchs [16384, 256] fp32 row-major, Bm = label2embed [4096, 256] fp32 row-major
// out [16384, 4096] fp32. GEMM-BT, K=256. Output-write floor: 43.7 us (268 MB @ 6.3 TB/s).
//
// Session ledger:
//  R0: fill(~167, unconditional ws poison) + [fill_out ~42?] + cvt(6) + gemm(~84-124) = 297.
//  R1: cvt fused into gemm -> 50x VALU cvt blowup. REVERTED.
//  R2: no-LDS direct-from-L2 fragments -> +80us. REVERTED (global_load_lds wins).
//  R3: swapped-operand MFMA + f32x4 epilogue -> NEUTRAL (not store-issue-bound).
//  R4: triple-buf + counted vmcnt pipeline -> NEUTRAL (not barrier-drain-bound).
//  R5: nontemporal epilogue -> NEUTRAL (not L2-eviction-bound).
//  R6 (this): gemm time ~= ZERO-overlap sum of its phases (write 105K + LDS 48K + L2 37K
//      + MFMA 10K cyc/CU). All single-phase levers neutral => the loss is phase overlap:
//      4 lockstep resident blocks drain their write bursts together, compute together.
//      Fix: residency. 128x64 tiles (24 KB LDS/block), __launch_bounds__(256,5) ->
//      5 blocks/CU, 8192 blocks, 2x smaller write bursts, finer interleave.
#define MDIM 16384
#define NDIM 4096
#define KDIM 256

#define BM 128
#define BN 64
#define BK 32
#define KSTEPS (KDIM / BK)   // 8

typedef __attribute__((ext_vector_type(8))) short bf16x8;
typedef __attribute__((ext_vector_type(4))) float f32x4;

__device__ __forceinline__ unsigned short f2bf_rne(float f) {
    union { float f; uint32_t u; } v; v.f = f;
    uint32_t u = v.u;
    u += 0x7fffu + ((u >> 16) & 1u);   // round-to-nearest-even (finite inputs)
    return (unsigned short)(u >> 16);
}

// Pass 1: fp32 -> bf16 for both inputs, into workspace. 8 elems/thread, 16B stores.
__global__ __launch_bounds__(256) void cvt_kernel(const float* __restrict__ a,
                                                  const float* __restrict__ b,
                                                  unsigned short* __restrict__ wa,
                                                  unsigned short* __restrict__ wb) {
    const int64_t nA = (int64_t)MDIM * KDIM;
    int64_t i = ((int64_t)blockIdx.x * 256 + threadIdx.x) * 8;
    const float* src; unsigned short* dst; int64_t off;
    if (i < nA) { src = a; dst = wa; off = i; }
    else        { src = b; dst = wb; off = i - nA; }
    float4 f0 = *(const float4*)(src + off);
    float4 f1 = *(const float4*)(src + off + 4);
    union { unsigned short h[8]; int4 v; } o;
    o.h[0] = f2bf_rne(f0.x); o.h[1] = f2bf_rne(f0.y);
    o.h[2] = f2bf_rne(f0.z); o.h[3] = f2bf_rne(f0.w);
    o.h[4] = f2bf_rne(f1.x); o.h[5] = f2bf_rne(f1.y);
    o.h[6] = f2bf_rne(f1.z); o.h[7] = f2bf_rne(f1.w);
    *(int4*)(dst + off) = o.v;
}

// Stage one 128x32 A-tile (512 granules, 2/thread) and one 64x32 B-tile (256 granules,
// 1/thread) into LDS via width-16 global_load_lds. granule g: row = g>>2, col = (g&3)*8,
// LDS byte off = g*16 (wave-uniform base + lane*16 matches HW placement).
__device__ __forceinline__ void stage_tiles(const unsigned short* __restrict__ Ab,
                                            const unsigned short* __restrict__ Bb,
                                            unsigned short* sA, unsigned short* sB,
                                            int tid, int k0) {
#pragma unroll
    for (int c = 0; c < 2; ++c) {
        int ch  = tid + c * 256;
        int row = ch >> 2;
        int col = (ch & 3) << 3;
        __builtin_amdgcn_global_load_lds(
            (const __attribute__((address_space(1))) void*)(Ab + (size_t)row * KDIM + k0 + col),
            (__attribute__((address_space(3))) void*)(sA + ch * 8), 16, 0, 0);
    }
    {
        int ch  = tid;
        int row = ch >> 2;
        int col = (ch & 3) << 3;
        __builtin_amdgcn_global_load_lds(
            (const __attribute__((address_space(1))) void*)(Bb + (size_t)row * KDIM + k0 + col),
            (__attribute__((address_space(3))) void*)(sB + ch * 8), 16, 0, 0);
    }
}

// Pass 2: bf16 MFMA GEMM-BT. 128x64 tile/block, 4 waves, each wave a 64x32 quadrant
// = 4x2 MFMA 16x16 tiles. BK=32, 8 K-steps, double-buffered LDS, one barrier/step.
// 24 KB LDS/block; __launch_bounds__(256,5): VGPR<=102 -> 5 blocks/CU, 20 waves/CU.
__global__ __launch_bounds__(256, 5) void gemm_bt(const unsigned short* __restrict__ A,
                                                  const unsigned short* __restrict__ Bm,
                                                  float* __restrict__ out) {
    __shared__ __align__(16) unsigned short sA[2][BM * BK];  // 2 x 8 KiB
    __shared__ __align__(16) unsigned short sB[2][BN * BK];  // 2 x 4 KiB

    const int tid  = threadIdx.x;
    const int lane = tid & 63;
    const int wave = tid >> 6;
    const int wm   = wave >> 1;          // 0..1 : row half
    const int wn   = wave & 1;           // 0..1 : col half
    const int quad = lane >> 4;
    const int r16  = lane & 15;

    // XCD-aware swizzle: xcd = blockIdx % 8. Each XCD owns a band of 16 bm's; bn sweeps
    // fastest -> per-XCD set = A band (1 MB) + full B (2 MB) = 3 MB < 4 MB XCD L2.
    // 8192 blocks: g in [0,1024): bm = xcd*16 + (g>>6) in [0,128), bn = g&63 in [0,64).
    const int id  = blockIdx.x;
    const int xcd = id & 7;
    const int g   = id >> 3;
    const int bm  = (xcd << 4) | (g >> 6);
    const int bn  = g & 63;

    const unsigned short* Ab = A  + (size_t)bm * BM * KDIM;
    const unsigned short* Bb = Bm + (size_t)bn * BN * KDIM;

    f32x4 acc[4][2] = {};

    stage_tiles(Ab, Bb, sA[0], sB[0], tid, 0);

#pragma unroll
    for (int step = 0; step < KSTEPS; ++step) {
        __syncthreads();  // drains vmcnt for buf[step&1]; WAR-protects buf[(step+1)&1]
        if (step + 1 < KSTEPS)
            stage_tiles(Ab, Bb, sA[(step + 1) & 1], sB[(step + 1) & 1], tid, (step + 1) * BK);

        const unsigned short* cA = sA[step & 1];
        const unsigned short* cB = sB[step & 1];

        // Fragment: X[row = lane&15][k = quad*8 + j]  (one ds_read_b128 each)
        bf16x8 af[4], bfr[2];
#pragma unroll
        for (int i = 0; i < 4; ++i)
            af[i] = *(const bf16x8*)(cA + ((wm * 64 + i * 16 + r16) * BK + quad * 8));
#pragma unroll
        for (int j = 0; j < 2; ++j)
            bfr[j] = *(const bf16x8*)(cB + ((wn * 32 + j * 16 + r16) * BK + quad * 8));

        // SWAPPED operands (validated R1-R5): D = mfma(bfr, af) ->
        // D col-field (lane&15) = out row, D row-field (quad*4+reg) = out col.
#pragma unroll
        for (int i = 0; i < 4; ++i)
#pragma unroll
            for (int j = 0; j < 2; ++j)
                acc[i][j] = __builtin_amdgcn_mfma_f32_16x16x32_bf16(bfr[j], af[i], acc[i][j], 0, 0, 0);
    }

    // Epilogue: 8 dwordx4 stores/lane; per instruction 16 rows x 64B contiguous.
#pragma unroll
    for (int i = 0; i < 4; ++i) {
        size_t row = (size_t)bm * BM + wm * 64 + i * 16 + r16;
#pragma unroll
        for (int j = 0; j < 2; ++j) {
            int col = bn * BN + wn * 32 + j * 16 + quad * 4;
            *(f32x4*)(out + row * NDIM + col) = acc[i][j];
        }
    }
}

// Fallback (only if ws too small): fp32 dot, one thread per output.
__global__ __launch_bounds__(256) void naive_f32(const float* __restrict__ a,
                                                 const float* __restrict__ b,
                                                 float* __restrict__ out) {
    int64_t idx = (int64_t)blockIdx.x * 256 + threadIdx.x;
    int c = (int)(idx & (NDIM - 1));
    int r = (int)(idx >> 12);
    const float4* ap = (const float4*)(a + (size_t)r * KDIM);
    const float4* bp = (const float4*)(b + (size_t)c * KDIM);
    float s = 0.f;
#pragma unroll 8
    for (int k = 0; k < KDIM / 4; ++k) {
        float4 x = ap[k], y = bp[k];
        s += x.x * y.x + x.y * y.y + x.z * y.z + x.w * y.w;
    }
    out[idx] = s;
}

extern "C" void kernel_launch(void* const* d_in, const int* in_sizes, int n_in,
                              void* d_out, int out_size, void* d_ws, size_t ws_size,
                              hipStream_t stream) {
    const float* a = (const float*)d_in[0];   // batchs  [16384, 2, 128]
    const float* b = (const float*)d_in[1];   // label2embed [4096, 2, 128]
    float* out = (float*)d_out;               // [16384, 4096]

    const size_t need = ((size_t)MDIM + NDIM) * KDIM * sizeof(unsigned short); // 10.5 MB
    if (d_ws != nullptr && ws_size >= need) {
        unsigned short* wa = (unsigned short*)d_ws;
        unsigned short* wb = wa + (size_t)MDIM * KDIM;
        const int64_t nvec = ((int64_t)MDIM + NDIM) * KDIM / 8;  // 655,360
        cvt_kernel<<<(int)(nvec / 256), 256, 0, stream>>>(a, b, wa, wb);       // 2560 blocks
        gemm_bt<<<(MDIM / BM) * (NDIM / BN), 256, 0, stream>>>(wa, wb, out);   // 8192 blocks
    } else {
        naive_f32<<<(int64_t)MDIM * NDIM / 256, 256, 0, stream>>>(a, b, out);
    }
}

// Round 7
// 298.852 us; speedup vs baseline: 1.0507x; 1.0393x over previous
//
#include <hip/hip_runtime.h>
#include <stdint.h>

// out[b,c] = sum_{k<256} batchs[b,k] * label2embed[c,k]
// A = batchs [16384, 256] fp32, Bm = label2embed [4096, 256] fp32, out [16384,4096] fp32.
// GEMM-BT, K=256. Pure-write ceiling (measured via harness fills): 6.4 TB/s -> 42 us for 268 MB.
//
// Session ledger:
//  R0: fill(~167 ws poison) + out-poison(~42) + cvt(6) + gemm(~82) = 297.
//  R1: cvt fused into gemm -> 50x VALU cvt blowup. REVERTED.
//  R2: no-LDS direct-from-L2 fragments -> +80us. REVERTED.
//  R3: f32x4 epilogue (64B segments) -> NEUTRAL.
//  R4: triple-buf + counted vmcnt -> NEUTRAL.  R5: nt stores -> NEUTRAL.
//  R6: 128x64 tiles, 5 blocks/CU -> NEUTRAL.
//  R7 (this): gemm writes at exactly HALF the demonstrated write BW. Theory that fits
//      all data: partial-sector stores (16 scattered 64B segments/instr) trigger
//      L2 fetch-on-write -> +268 MB RFO read: (268+268)/6.5 TB/s = 82 us = measured.
//      Fix: LDS-transposed epilogue; each wave store instr covers 2 rows x 512B fully
//      contiguous (whole 128B lines) -> no partial sectors -> no RFO.
#define MDIM 16384
#define NDIM 4096
#define KDIM 256

#define BM 128
#define BN 128
#define BK 32
#define KSTEPS (KDIM / BK)   // 8

typedef __attribute__((ext_vector_type(8))) short bf16x8;
typedef __attribute__((ext_vector_type(4))) float f32x4;

__device__ __forceinline__ unsigned short f2bf_rne(float f) {
    union { float f; uint32_t u; } v; v.f = f;
    uint32_t u = v.u;
    u += 0x7fffu + ((u >> 16) & 1u);   // round-to-nearest-even (finite inputs)
    return (unsigned short)(u >> 16);
}

// Pass 1: fp32 -> bf16 for both inputs, into workspace. 8 elems/thread, 16B stores.
__global__ __launch_bounds__(256) void cvt_kernel(const float* __restrict__ a,
                                                  const float* __restrict__ b,
                                                  unsigned short* __restrict__ wa,
                                                  unsigned short* __restrict__ wb) {
    const int64_t nA = (int64_t)MDIM * KDIM;
    int64_t i = ((int64_t)blockIdx.x * 256 + threadIdx.x) * 8;
    const float* src; unsigned short* dst; int64_t off;
    if (i < nA) { src = a; dst = wa; off = i; }
    else        { src = b; dst = wb; off = i - nA; }
    float4 f0 = *(const float4*)(src + off);
    float4 f1 = *(const float4*)(src + off + 4);
    union { unsigned short h[8]; int4 v; } o;
    o.h[0] = f2bf_rne(f0.x); o.h[1] = f2bf_rne(f0.y);
    o.h[2] = f2bf_rne(f0.z); o.h[3] = f2bf_rne(f0.w);
    o.h[4] = f2bf_rne(f1.x); o.h[5] = f2bf_rne(f1.y);
    o.h[6] = f2bf_rne(f1.z); o.h[7] = f2bf_rne(f1.w);
    *(int4*)(dst + off) = o.v;
}

// Stage one 128x32 bf16 tile of A and B into LDS via width-16 global_load_lds.
// chunk ch in [0,512): row = ch>>2, col = (ch&3)*8; LDS byte off = ch*16.
__device__ __forceinline__ void stage_tiles(const unsigned short* __restrict__ Ab,
                                            const unsigned short* __restrict__ Bb,
                                            unsigned short* sA, unsigned short* sB,
                                            int tid, int k0) {
#pragma unroll
    for (int c = 0; c < 2; ++c) {
        int ch  = tid + c * 256;
        int row = ch >> 2;
        int col = (ch & 3) << 3;
        __builtin_amdgcn_global_load_lds(
            (const __attribute__((address_space(1))) void*)(Ab + (size_t)row * KDIM + k0 + col),
            (__attribute__((address_space(3))) void*)(sA + ch * 8), 16, 0, 0);
        __builtin_amdgcn_global_load_lds(
            (const __attribute__((address_space(1))) void*)(Bb + (size_t)row * KDIM + k0 + col),
            (__attribute__((address_space(3))) void*)(sB + ch * 8), 16, 0, 0);
    }
}

// Pass 2: bf16 MFMA GEMM-BT. 128x128 tile/block, 4 waves, each wave a 64x64 quadrant
// = 4x4 MFMA 16x16 tiles. BK=32, 8 K-steps, double-buffered LDS, one barrier/step
// (identical to R3, the best-measured loop). NEW: LDS-transposed epilogue.
__global__ __launch_bounds__(256, 4) void gemm_bt(const unsigned short* __restrict__ A,
                                                  const unsigned short* __restrict__ Bm,
                                                  float* __restrict__ out) {
    __shared__ __align__(16) unsigned short sA[2][BM * BK];  // 2 x 8 KiB
    __shared__ __align__(16) unsigned short sB[2][BN * BK];  // 2 x 8 KiB

    const int tid  = threadIdx.x;
    const int lane = tid & 63;
    const int wave = tid >> 6;
    const int wm   = wave >> 1;
    const int wn   = wave & 1;
    const int quad = lane >> 4;
    const int r16  = lane & 15;

    // XCD-aware swizzle: each XCD owns a band of 16 bm's; bn sweeps fastest ->
    // per-XCD set = A band (1 MB) + full B (2 MB) = 3 MB < 4 MB XCD L2.
    const int id  = blockIdx.x;
    const int xcd = id & 7;
    const int g   = id >> 3;                // 0..511
    const int bm  = (xcd << 4) | (g >> 5);  // 0..127
    const int bn  = g & 31;                 // 0..31

    const unsigned short* Ab = A  + (size_t)bm * BM * KDIM;
    const unsigned short* Bb = Bm + (size_t)bn * BN * KDIM;

    f32x4 acc[4][4] = {};

    stage_tiles(Ab, Bb, sA[0], sB[0], tid, 0);

#pragma unroll
    for (int step = 0; step < KSTEPS; ++step) {
        __syncthreads();  // drains vmcnt for buf[step&1]; WAR-protects buf[(step+1)&1]
        if (step + 1 < KSTEPS)
            stage_tiles(Ab, Bb, sA[(step + 1) & 1], sB[(step + 1) & 1], tid, (step + 1) * BK);

        const unsigned short* cA = sA[step & 1];
        const unsigned short* cB = sB[step & 1];

        // Fragment: X[row = lane&15][k = quad*8 + j]  (one ds_read_b128 each)
        bf16x8 af[4], bfr[4];
#pragma unroll
        for (int i = 0; i < 4; ++i)
            af[i] = *(const bf16x8*)(cA + ((wm * 64 + i * 16 + r16) * BK + quad * 8));
#pragma unroll
        for (int j = 0; j < 4; ++j)
            bfr[j] = *(const bf16x8*)(cB + ((wn * 64 + j * 16 + r16) * BK + quad * 8));

        // SWAPPED operands (validated R1-R6): D = mfma(bfr, af) ->
        // lane holds out[row = wm*64+i*16+r16][col = wn*64+j*16+quad*4 .. +3].
#pragma unroll
        for (int i = 0; i < 4; ++i)
#pragma unroll
            for (int j = 0; j < 4; ++j)
                acc[i][j] = __builtin_amdgcn_mfma_f32_16x16x32_bf16(bfr[j], af[i], acc[i][j], 0, 0, 0);
    }

    // ---- Epilogue: LDS-transposed, full-line global stores ----
    // 4 chunks of 32 rows x 128 cols f32 (16 KiB, reuses sA). Write side: the 2 waves
    // owning the chunk's rows dump acc via swizzled ds_write_b128 (XOR 16B-unit by
    // rowc&7 -> 8 lanes per 16B slot, even = conflict-free). Read side: all 256 thr
    // stream linearly; per wave instruction = 2 rows x 512B CONTIGUOUS global stores
    // (4 full 128B lines per segment -> no partial-sector writes -> no RFO).
    float* fb = (float*)&sA[0][0];   // 16 KiB scratch
#pragma unroll
    for (int c = 0; c < 4; ++c) {
        __syncthreads();   // buffer free: K-loop reads done (c=0) / prev chunk streamed
        if (wm == (c >> 1)) {
#pragma unroll
            for (int ii = 0; ii < 2; ++ii) {
                const int i    = ((c & 1) << 1) | ii;        // acc row-tile index
                const int rowc = ii * 16 + r16;              // row within chunk 0..31
                const int sw   = (rowc & 7) << 2;            // float-idx XOR (16B units)
#pragma unroll
                for (int j = 0; j < 4; ++j) {
                    const int colf = wn * 64 + j * 16 + quad * 4;   // float col 0..127
                    *(f32x4*)(fb + rowc * 128 + (colf ^ sw)) = acc[i][j];
                }
            }
        }
        __syncthreads();
#pragma unroll
        for (int p = 0; p < 4; ++p) {
            const int fidx = p * 1024 + tid * 4;             // float idx in 32x128 chunk
            const int rowc = fidx >> 7;
            const int colf = fidx & 127;
            f32x4 v = *(const f32x4*)(fb + rowc * 128 + (colf ^ ((rowc & 7) << 2)));
            *(f32x4*)(out + (size_t)(bm * BM + c * 32 + rowc) * NDIM + bn * BN + colf) = v;
        }
    }
}

// Fallback (only if ws too small): fp32 dot, one thread per output.
__global__ __launch_bounds__(256) void naive_f32(const float* __restrict__ a,
                                                 const float* __restrict__ b,
                                                 float* __restrict__ out) {
    int64_t idx = (int64_t)blockIdx.x * 256 + threadIdx.x;
    int c = (int)(idx & (NDIM - 1));
    int r = (int)(idx >> 12);
    const float4* ap = (const float4*)(a + (size_t)r * KDIM);
    const float4* bp = (const float4*)(b + (size_t)c * KDIM);
    float s = 0.f;
#pragma unroll 8
    for (int k = 0; k < KDIM / 4; ++k) {
        float4 x = ap[k], y = bp[k];
        s += x.x * y.x + x.y * y.y + x.z * y.z + x.w * y.w;
    }
    out[idx] = s;
}

extern "C" void kernel_launch(void* const* d_in, const int* in_sizes, int n_in,
                              void* d_out, int out_size, void* d_ws, size_t ws_size,
                              hipStream_t stream) {
    const float* a = (const float*)d_in[0];   // batchs  [16384, 2, 128]
    const float* b = (const float*)d_in[1];   // label2embed [4096, 2, 128]
    float* out = (float*)d_out;               // [16384, 4096]

    const size_t need = ((size_t)MDIM + NDIM) * KDIM * sizeof(unsigned short); // 10.5 MB
    if (d_ws != nullptr && ws_size >= need) {
        unsigned short* wa = (unsigned short*)d_ws;
        unsigned short* wb = wa + (size_t)MDIM * KDIM;
        const int64_t nvec = ((int64_t)MDIM + NDIM) * KDIM / 8;  // 655,360
        cvt_kernel<<<(int)(nvec / 256), 256, 0, stream>>>(a, b, wa, wb);       // 2560 blocks
        gemm_bt<<<(MDIM / BM) * (NDIM / BN), 256, 0, stream>>>(wa, wb, out);   // 4096 blocks
    } else {
        naive_f32<<<(int64_t)MDIM * NDIM / 256, 256, 0, stream>>>(a, b, out);
    }
}